// Round 1
// baseline (610.741 us; speedup 1.0000x reference)
//
#include <hip/hip_runtime.h>

#define W 144
#define PLANE (144 * 144)
#define VOL (144 * 144 * 144)
#define NB 2
#define NFIELD 5
#define WIN 11
#define PAD 5
#define ZCHUNKS 3
#define ZCHUNK (W / ZCHUNKS)

__device__ __forceinline__ void block_reduce_atomic(float val, float* red, double* acc) {
    const int x = threadIdx.x;
    red[x] = val;
    __syncthreads();
    if (x < 16) {
        float s2 = 0.f;
#pragma unroll
        for (int k = 0; k < 9; ++k) s2 += red[x + 16 * k];
        s2 += __shfl_down(s2, 8);
        s2 += __shfl_down(s2, 4);
        s2 += __shfl_down(s2, 2);
        s2 += __shfl_down(s2, 1);
        if (x == 0) atomicAdd(acc, (double)s2);
    }
}

// K1: per (b,z,y) line: compute 5 raw fields, window-sum along x (LDS), store.
// Also accumulate sum |p-t|.
__global__ void k1_xpass(const float* __restrict__ pred, const float* __restrict__ targ,
                         float* __restrict__ ws, double* __restrict__ acc) {
    const int x = threadIdx.x;
    int bid = blockIdx.x;
    const int y = bid % W; bid /= W;
    const int z = bid % W; bid /= W;
    const int b = bid;
    const int base = b * VOL + z * PLANE + y * W;

    __shared__ float sp[W + 2 * PAD];
    __shared__ float st[W + 2 * PAD];
    __shared__ float red[W];

    const float p = pred[base + x];
    const float t = targ[base + x];
    sp[PAD + x] = p;
    st[PAD + x] = t;
    if (x < PAD) {
        sp[x] = 0.f; st[x] = 0.f;
        sp[PAD + W + x] = 0.f; st[PAD + W + x] = 0.f;
    }
    __syncthreads();

    float s_p = 0.f, s_t = 0.f, s_pp = 0.f, s_tt = 0.f, s_pt = 0.f;
#pragma unroll
    for (int k = 0; k < WIN; ++k) {
        const float pj = sp[x + k];
        const float tj = st[x + k];
        s_p += pj;
        s_t += tj;
        s_pp = fmaf(pj, pj, s_pp);
        s_tt = fmaf(tj, tj, s_tt);
        s_pt = fmaf(pj, tj, s_pt);
    }
    const int o = z * PLANE + y * W + x;
    ws[(0 * NB + b) * VOL + o] = s_p;
    ws[(1 * NB + b) * VOL + o] = s_t;
    ws[(2 * NB + b) * VOL + o] = s_pp;
    ws[(3 * NB + b) * VOL + o] = s_tt;
    ws[(4 * NB + b) * VOL + o] = s_pt;

    block_reduce_atomic(fabsf(p - t), red, acc);  // acc[0] = L1 sum
}

// K2: in-place window-sum along y. One column (fixed f,b,z,x) per thread,
// running sum with 11-deep shift register (all static indices).
__global__ void k2_ypass(float* __restrict__ ws) {
    const int x = threadIdx.x;
    int bid = blockIdx.x;
    const int z = bid % W; bid /= W;
    const int b = bid % NB; bid /= NB;
    const int f = bid;
    float* col = ws + (f * NB + b) * VOL + z * PLANE + x;

    float w[WIN];
#pragma unroll
    for (int k = 0; k < WIN; ++k) w[k] = 0.f;
    float s = 0.f;
    for (int yl = 0; yl < W + PAD; ++yl) {
        const float v = (yl < W) ? col[yl * W] : 0.f;
        s += v - w[0];
#pragma unroll
        for (int k = 0; k < WIN - 1; ++k) w[k] = w[k + 1];
        w[WIN - 1] = v;
        if (yl >= PAD) col[(yl - PAD) * W] = s;
    }
}

// K3: window-sum along z for all 5 fields (read-only scan, z chunked x3),
// compute SSIM per voxel, block-reduce into acc[1].
__global__ void k3_zpass(const float* __restrict__ ws, double* __restrict__ acc) {
    const int x = threadIdx.x;
    int bid = blockIdx.x;
    const int c = bid % ZCHUNKS; bid /= ZCHUNKS;
    const int y = bid % W; bid /= W;
    const int b = bid;
    const int zstart = c * ZCHUNK;

    const float* F[NFIELD];
#pragma unroll
    for (int f = 0; f < NFIELD; ++f) F[f] = ws + (f * NB + b) * VOL + y * W + x;

    float wr[NFIELD][WIN];
    float sm[NFIELD];
#pragma unroll
    for (int f = 0; f < NFIELD; ++f) {
        sm[f] = 0.f;
#pragma unroll
        for (int k = 0; k < WIN; ++k) wr[f][k] = 0.f;
    }

    const float inv = 1.0f / 1331.0f;
    const float C1 = 0.01f * 0.01f;
    const float C2 = 0.03f * 0.03f;
    float ssim_acc = 0.f;

    for (int i = 0; i < ZCHUNK + 2 * PAD; ++i) {
        const int zl = zstart - PAD + i;
        const bool inb = (zl >= 0) && (zl < W);
        const int zoff = zl * PLANE;
#pragma unroll
        for (int f = 0; f < NFIELD; ++f) {
            const float v = inb ? F[f][zoff] : 0.f;
            sm[f] += v - wr[f][0];
#pragma unroll
            for (int k = 0; k < WIN - 1; ++k) wr[f][k] = wr[f][k + 1];
            wr[f][WIN - 1] = v;
        }
        if (i >= 2 * PAD) {
            const float mu_p = sm[0] * inv;
            const float mu_t = sm[1] * inv;
            const float ep2 = sm[2] * inv;
            const float et2 = sm[3] * inv;
            const float ept = sm[4] * inv;
            const float mupt = mu_p * mu_t;
            const float sig_p = ep2 - mu_p * mu_p;
            const float sig_t = et2 - mu_t * mu_t;
            const float sig_pt = ept - mupt;
            const float num = (2.f * mupt + C1) * (2.f * sig_pt + C2);
            const float den = (mu_p * mu_p + mu_t * mu_t + C1) * (sig_p + sig_t + C2);
            ssim_acc += num / den;
        }
    }

    __shared__ float red[W];
    block_reduce_atomic(ssim_acc, red, acc + 1);  // acc[1] = SSIM sum
}

__global__ void k4_final(const double* __restrict__ acc, float* __restrict__ out) {
    const double n = (double)NB * (double)VOL;
    const double l1 = acc[0] / n;
    const double ssim_mean = acc[1] / n;
    const double ssim_loss = 1.0 - ssim_mean;
    const double total = 1.0 * l1 + 0.5 * ssim_loss;
    out[0] = (float)total;
    out[1] = (float)l1;
    out[2] = (float)ssim_loss;
}

extern "C" void kernel_launch(void* const* d_in, const int* in_sizes, int n_in,
                              void* d_out, int out_size, void* d_ws, size_t ws_size,
                              hipStream_t stream) {
    const float* pred = (const float*)d_in[0];
    const float* targ = (const float*)d_in[1];
    float* out = (float*)d_out;
    float* ws = (float*)d_ws;
    double* acc = (double*)((char*)d_ws + (size_t)NFIELD * NB * VOL * sizeof(float));

    hipMemsetAsync(acc, 0, 2 * sizeof(double), stream);
    k1_xpass<<<NB * W * W, W, 0, stream>>>(pred, targ, ws, acc);
    k2_ypass<<<NFIELD * NB * W, W, 0, stream>>>(ws);
    k3_zpass<<<NB * W * ZCHUNKS, W, 0, stream>>>(ws, acc);
    k4_final<<<1, 1, 0, stream>>>(acc, out);
}

// Round 2
// 138.037 us; speedup vs baseline: 4.4245x; 4.4245x over previous
//
#include <hip/hip_runtime.h>

#define W 144
#define PLANE (144 * 144)
#define VOL (144 * 144 * 144)
#define NB 2
#define NFIELD 5
#define WIN 11
#define PAD 5
#define ZCHUNKS 3
#define ZCHUNK (W / ZCHUNKS)
#define NCELL 256  // accumulator cells to spread atomic contention

__device__ __forceinline__ void block_reduce_atomic(float val, float* red, double* cell) {
    const int x = threadIdx.x;
    red[x] = val;
    __syncthreads();
    if (x < 16) {
        float s2 = 0.f;
#pragma unroll
        for (int k = 0; k < 9; ++k) s2 += red[x + 16 * k];
        s2 += __shfl_down(s2, 8);
        s2 += __shfl_down(s2, 4);
        s2 += __shfl_down(s2, 2);
        s2 += __shfl_down(s2, 1);
        if (x == 0) atomicAdd(cell, (double)s2);
    }
}

// K1: per (b,z,y) line: compute 5 raw fields, window-sum along x (LDS), store.
// Also accumulate sum |p-t| into spread cells.
__global__ void k1_xpass(const float* __restrict__ pred, const float* __restrict__ targ,
                         float* __restrict__ ws, double* __restrict__ accL1) {
    const int x = threadIdx.x;
    int bid = blockIdx.x;
    const int y = bid % W; bid /= W;
    const int z = bid % W; bid /= W;
    const int b = bid;
    const int base = b * VOL + z * PLANE + y * W;

    __shared__ float sp[W + 2 * PAD];
    __shared__ float st[W + 2 * PAD];
    __shared__ float red[W];

    const float p = pred[base + x];
    const float t = targ[base + x];
    sp[PAD + x] = p;
    st[PAD + x] = t;
    if (x < PAD) {
        sp[x] = 0.f; st[x] = 0.f;
        sp[PAD + W + x] = 0.f; st[PAD + W + x] = 0.f;
    }
    __syncthreads();

    float s_p = 0.f, s_t = 0.f, s_pp = 0.f, s_tt = 0.f, s_pt = 0.f;
#pragma unroll
    for (int k = 0; k < WIN; ++k) {
        const float pj = sp[x + k];
        const float tj = st[x + k];
        s_p += pj;
        s_t += tj;
        s_pp = fmaf(pj, pj, s_pp);
        s_tt = fmaf(tj, tj, s_tt);
        s_pt = fmaf(pj, tj, s_pt);
    }
    const int o = z * PLANE + y * W + x;
    ws[(0 * NB + b) * VOL + o] = s_p;
    ws[(1 * NB + b) * VOL + o] = s_t;
    ws[(2 * NB + b) * VOL + o] = s_pp;
    ws[(3 * NB + b) * VOL + o] = s_tt;
    ws[(4 * NB + b) * VOL + o] = s_pt;

    block_reduce_atomic(fabsf(p - t), red, &accL1[blockIdx.x & (NCELL - 1)]);
}

// K2: in-place window-sum along y. One column (fixed f,b,z,x) per thread,
// running sum with 11-deep shift register (all static indices).
__global__ void k2_ypass(float* __restrict__ ws) {
    const int x = threadIdx.x;
    int bid = blockIdx.x;
    const int z = bid % W; bid /= W;
    const int b = bid % NB; bid /= NB;
    const int f = bid;
    float* col = ws + (f * NB + b) * VOL + z * PLANE + x;

    float w[WIN];
#pragma unroll
    for (int k = 0; k < WIN; ++k) w[k] = 0.f;
    float s = 0.f;
    for (int yl = 0; yl < W + PAD; ++yl) {
        const float v = (yl < W) ? col[yl * W] : 0.f;
        s += v - w[0];
#pragma unroll
        for (int k = 0; k < WIN - 1; ++k) w[k] = w[k + 1];
        w[WIN - 1] = v;
        if (yl >= PAD) col[(yl - PAD) * W] = s;
    }
}

// K3: window-sum along z for all 5 fields (read-only scan, z chunked x3),
// compute SSIM per voxel, block-reduce into spread cells.
__global__ void k3_zpass(const float* __restrict__ ws, double* __restrict__ accS) {
    const int x = threadIdx.x;
    int bid = blockIdx.x;
    const int c = bid % ZCHUNKS; bid /= ZCHUNKS;
    const int y = bid % W; bid /= W;
    const int b = bid;
    const int zstart = c * ZCHUNK;

    const float* F[NFIELD];
#pragma unroll
    for (int f = 0; f < NFIELD; ++f) F[f] = ws + (f * NB + b) * VOL + y * W + x;

    float wr[NFIELD][WIN];
    float sm[NFIELD];
#pragma unroll
    for (int f = 0; f < NFIELD; ++f) {
        sm[f] = 0.f;
#pragma unroll
        for (int k = 0; k < WIN; ++k) wr[f][k] = 0.f;
    }

    const float inv = 1.0f / 1331.0f;
    const float C1 = 0.01f * 0.01f;
    const float C2 = 0.03f * 0.03f;
    float ssim_acc = 0.f;

    for (int i = 0; i < ZCHUNK + 2 * PAD; ++i) {
        const int zl = zstart - PAD + i;
        const bool inb = (zl >= 0) && (zl < W);
        const int zoff = zl * PLANE;
#pragma unroll
        for (int f = 0; f < NFIELD; ++f) {
            const float v = inb ? F[f][zoff] : 0.f;
            sm[f] += v - wr[f][0];
#pragma unroll
            for (int k = 0; k < WIN - 1; ++k) wr[f][k] = wr[f][k + 1];
            wr[f][WIN - 1] = v;
        }
        if (i >= 2 * PAD) {
            const float mu_p = sm[0] * inv;
            const float mu_t = sm[1] * inv;
            const float ep2 = sm[2] * inv;
            const float et2 = sm[3] * inv;
            const float ept = sm[4] * inv;
            const float mupt = mu_p * mu_t;
            const float sig_p = ep2 - mu_p * mu_p;
            const float sig_t = et2 - mu_t * mu_t;
            const float sig_pt = ept - mupt;
            const float num = (2.f * mupt + C1) * (2.f * sig_pt + C2);
            const float den = (mu_p * mu_p + mu_t * mu_t + C1) * (sig_p + sig_t + C2);
            ssim_acc += num / den;
        }
    }

    __shared__ float red[W];
    block_reduce_atomic(ssim_acc, red, &accS[blockIdx.x & (NCELL - 1)]);
}

// K4: reduce the 2x256 cells, write the 3 outputs.
__global__ void k4_final(const double* __restrict__ accL1, const double* __restrict__ accS,
                         float* __restrict__ out) {
    const int x = threadIdx.x;
    __shared__ double r1[NCELL];
    __shared__ double r2[NCELL];
    r1[x] = accL1[x];
    r2[x] = accS[x];
    __syncthreads();
    for (int s = NCELL / 2; s > 0; s >>= 1) {
        if (x < s) {
            r1[x] += r1[x + s];
            r2[x] += r2[x + s];
        }
        __syncthreads();
    }
    if (x == 0) {
        const double n = (double)NB * (double)VOL;
        const double l1 = r1[0] / n;
        const double ssim_loss = 1.0 - r2[0] / n;
        const double total = l1 + 0.5 * ssim_loss;
        out[0] = (float)total;
        out[1] = (float)l1;
        out[2] = (float)ssim_loss;
    }
}

extern "C" void kernel_launch(void* const* d_in, const int* in_sizes, int n_in,
                              void* d_out, int out_size, void* d_ws, size_t ws_size,
                              hipStream_t stream) {
    const float* pred = (const float*)d_in[0];
    const float* targ = (const float*)d_in[1];
    float* out = (float*)d_out;
    float* ws = (float*)d_ws;
    double* accL1 = (double*)((char*)d_ws + (size_t)NFIELD * NB * VOL * sizeof(float));
    double* accS = accL1 + NCELL;

    hipMemsetAsync(accL1, 0, 2 * NCELL * sizeof(double), stream);
    k1_xpass<<<NB * W * W, W, 0, stream>>>(pred, targ, ws, accL1);
    k2_ypass<<<NFIELD * NB * W, W, 0, stream>>>(ws);
    k3_zpass<<<NB * W * ZCHUNKS, W, 0, stream>>>(ws, accS);
    k4_final<<<1, NCELL, 0, stream>>>(accL1, accS, out);
}

// Round 3
// 81.893 us; speedup vs baseline: 7.4578x; 1.6856x over previous
//
#include <hip/hip_runtime.h>

#define W 144
#define PLANE (144 * 144)
#define VOL (144 * 144 * 144)
#define NB 2
#define NFIELD 4   // {sum_p, sum_t, sum_pt, sum_(p^2+t^2)}
#define WIN 11
#define PAD 5
#define YCHUNKS 4
#define YC (W / YCHUNKS)
#define ZCHUNKS 3
#define ZCHUNK (W / ZCHUNKS)
#define NCELL 256

__device__ __forceinline__ void block_reduce_atomic(float val, float* red, double* cell) {
    const int x = threadIdx.x;
    red[x] = val;
    __syncthreads();
    if (x < 16) {
        float s2 = 0.f;
#pragma unroll
        for (int k = 0; k < 9; ++k) s2 += red[x + 16 * k];
        s2 += __shfl_down(s2, 8);
        s2 += __shfl_down(s2, 4);
        s2 += __shfl_down(s2, 2);
        s2 += __shfl_down(s2, 1);
        if (x == 0) atomicAdd(cell, (double)s2);
    }
}

// K12: fused x+y pass. Block = (b, z, y-chunk); thread = x. Stream y:
// stage input row in double-buffered LDS line (zero halos), 11-tap x-window
// sums per lane, then 11-deep static ring (unrolled) for the y running sum.
// Writes 4 xy-summed fields. Also accumulates sum|p-t| on owned rows.
__global__ void k12_xypass(const float* __restrict__ pred, const float* __restrict__ targ,
                           float* __restrict__ ws, double* __restrict__ accL1) {
    const int x = threadIdx.x;
    int bid = blockIdx.x;
    const int yc = bid % YCHUNKS; bid /= YCHUNKS;
    const int z = bid % W; bid /= W;
    const int b = bid;
    const int y0 = yc * YC;
    const int base = b * VOL + z * PLANE;

    __shared__ float sp[2][W + 2 * PAD];
    __shared__ float st[2][W + 2 * PAD];
    __shared__ float red[W];

    if (x < PAD) {
        sp[0][x] = 0.f; sp[0][PAD + W + x] = 0.f;
        sp[1][x] = 0.f; sp[1][PAD + W + x] = 0.f;
        st[0][x] = 0.f; st[0][PAD + W + x] = 0.f;
        st[1][x] = 0.f; st[1][PAD + W + x] = 0.f;
    }

    float ring[NFIELD][WIN];
    float s4[NFIELD];
#pragma unroll
    for (int f = 0; f < NFIELD; ++f) {
        s4[f] = 0.f;
#pragma unroll
        for (int k = 0; k < WIN; ++k) ring[f][k] = 0.f;
    }
    float l1 = 0.f;

    const int yl_start = (y0 >= PAD) ? (y0 - PAD) : 0;
    const int yl_end = y0 + YC + PAD;  // exclusive
    const int outbase = z * PLANE + x;

    for (int c = 0; c < 5; ++c) {
#pragma unroll
        for (int u = 0; u < WIN; ++u) {
            const int i = c * WIN + u;
            const int yl = yl_start + i;
            if (yl < yl_end) {  // block-uniform guard
                float p = 0.f, t = 0.f;
                if (yl < W) {
                    p = pred[base + yl * W + x];
                    t = targ[base + yl * W + x];
                }
                const int pb = i & 1;
                sp[pb][PAD + x] = p;
                st[pb][PAD + x] = t;
                __syncthreads();

                if (yl >= y0 && yl < y0 + YC) l1 += fabsf(p - t);

                float sx0 = 0.f, sx1 = 0.f, sx2 = 0.f, sx3 = 0.f;
#pragma unroll
                for (int k = 0; k < WIN; ++k) {
                    const float pj = sp[pb][x + k];
                    const float tj = st[pb][x + k];
                    sx0 += pj;
                    sx1 += tj;
                    sx2 = fmaf(pj, tj, sx2);
                    sx3 = fmaf(pj, pj, sx3);
                    sx3 = fmaf(tj, tj, sx3);
                }
                // y-window running sum, static ring slot u
                s4[0] += sx0 - ring[0][u]; ring[0][u] = sx0;
                s4[1] += sx1 - ring[1][u]; ring[1][u] = sx1;
                s4[2] += sx2 - ring[2][u]; ring[2][u] = sx2;
                s4[3] += sx3 - ring[3][u]; ring[3][u] = sx3;

                const int y_out = yl - PAD;
                if (y_out >= y0) {
                    const int o = outbase + y_out * W;
                    ws[(0 * NB + b) * VOL + o] = s4[0];
                    ws[(1 * NB + b) * VOL + o] = s4[1];
                    ws[(2 * NB + b) * VOL + o] = s4[2];
                    ws[(3 * NB + b) * VOL + o] = s4[3];
                }
            }
        }
    }

    block_reduce_atomic(l1, red, &accL1[blockIdx.x & (NCELL - 1)]);
}

// K3: z-window running sum (static ring, unrolled) over 4 fields + SSIM + reduce.
__global__ void k3_zpass(const float* __restrict__ ws, double* __restrict__ accS) {
    const int x = threadIdx.x;
    int bid = blockIdx.x;
    const int c = bid % ZCHUNKS; bid /= ZCHUNKS;
    const int y = bid % W; bid /= W;
    const int b = bid;
    const int zstart = c * ZCHUNK;

    const float* F0 = ws + (0 * NB + b) * VOL + y * W + x;
    const float* F1 = ws + (1 * NB + b) * VOL + y * W + x;
    const float* F2 = ws + (2 * NB + b) * VOL + y * W + x;
    const float* F3 = ws + (3 * NB + b) * VOL + y * W + x;

    float ring[NFIELD][WIN];
    float sm[NFIELD];
#pragma unroll
    for (int f = 0; f < NFIELD; ++f) {
        sm[f] = 0.f;
#pragma unroll
        for (int k = 0; k < WIN; ++k) ring[f][k] = 0.f;
    }

    const float inv = 1.0f / 1331.0f;
    const float C1 = 0.01f * 0.01f;
    const float C2 = 0.03f * 0.03f;
    float ssim_acc = 0.f;

    const int NSTEP = ZCHUNK + 2 * PAD;  // 58
    for (int cc = 0; cc < 6; ++cc) {
#pragma unroll
        for (int u = 0; u < WIN; ++u) {
            const int i = cc * WIN + u;
            if (i < NSTEP) {
                const int zl = zstart - PAD + i;
                const bool inb = (zl >= 0) && (zl < W);
                const int zoff = zl * PLANE;
                const float v0 = inb ? F0[zoff] : 0.f;
                const float v1 = inb ? F1[zoff] : 0.f;
                const float v2 = inb ? F2[zoff] : 0.f;
                const float v3 = inb ? F3[zoff] : 0.f;
                sm[0] += v0 - ring[0][u]; ring[0][u] = v0;
                sm[1] += v1 - ring[1][u]; ring[1][u] = v1;
                sm[2] += v2 - ring[2][u]; ring[2][u] = v2;
                sm[3] += v3 - ring[3][u]; ring[3][u] = v3;
                if (i >= 2 * PAD) {
                    const float mu_p = sm[0] * inv;
                    const float mu_t = sm[1] * inv;
                    const float ept = sm[2] * inv;
                    const float esq = sm[3] * inv;
                    const float mupt = mu_p * mu_t;
                    const float musq = mu_p * mu_p + mu_t * mu_t;
                    const float sig_pt = ept - mupt;
                    const float sigsum = esq - musq;
                    const float num = (2.f * mupt + C1) * (2.f * sig_pt + C2);
                    const float den = (musq + C1) * (sigsum + C2);
                    ssim_acc += num / den;
                }
            }
        }
    }

    __shared__ float red[W];
    block_reduce_atomic(ssim_acc, red, &accS[blockIdx.x & (NCELL - 1)]);
}

// K4: reduce the 2x256 cells, write the 3 outputs.
__global__ void k4_final(const double* __restrict__ accL1, const double* __restrict__ accS,
                         float* __restrict__ out) {
    const int x = threadIdx.x;
    __shared__ double r1[NCELL];
    __shared__ double r2[NCELL];
    r1[x] = accL1[x];
    r2[x] = accS[x];
    __syncthreads();
    for (int s = NCELL / 2; s > 0; s >>= 1) {
        if (x < s) {
            r1[x] += r1[x + s];
            r2[x] += r2[x + s];
        }
        __syncthreads();
    }
    if (x == 0) {
        const double n = (double)NB * (double)VOL;
        const double l1 = r1[0] / n;
        const double ssim_loss = 1.0 - r2[0] / n;
        const double total = l1 + 0.5 * ssim_loss;
        out[0] = (float)total;
        out[1] = (float)l1;
        out[2] = (float)ssim_loss;
    }
}

extern "C" void kernel_launch(void* const* d_in, const int* in_sizes, int n_in,
                              void* d_out, int out_size, void* d_ws, size_t ws_size,
                              hipStream_t stream) {
    const float* pred = (const float*)d_in[0];
    const float* targ = (const float*)d_in[1];
    float* out = (float*)d_out;
    float* ws = (float*)d_ws;
    double* accL1 = (double*)((char*)d_ws + (size_t)NFIELD * NB * VOL * sizeof(float));
    double* accS = accL1 + NCELL;

    hipMemsetAsync(accL1, 0, 2 * NCELL * sizeof(double), stream);
    k12_xypass<<<NB * W * YCHUNKS, W, 0, stream>>>(pred, targ, ws, accL1);
    k3_zpass<<<NB * W * ZCHUNKS, W, 0, stream>>>(ws, accS);
    k4_final<<<1, NCELL, 0, stream>>>(accL1, accS, out);
}